// Round 13
// baseline (135.561 us; speedup 1.0000x reference)
//
#include <hip/hip_runtime.h>

#define T_ 3
#define B_ 4
#define N_ 4096
#define K_ 8

// Mega interleave: 32 groups of 44 blocks = 32 KNN + 12 chamfer.
#define GROUPS 32
#define GRP_KNN 32
#define GRP_CH  12
#define GRP_SZ  44
#define CWIN 512
#define NWIN (N_ / CWIN)  // 8

// Prefab A-fragment clouds in d_ws: dp[t*B+b]=0..11, src[b]=12..15, tp[b]=16..19.
// Cloud layout = LDS window layout: uint4 index ((cloud*8 + w)*1024 + tile*32 + slice*16 + m).
#define NCONV_BLOCKS 320  // 20 clouds * 4096 / 256
#define SL_BLOCKS    32

typedef short bf16x8 __attribute__((ext_vector_type(8)));
typedef float f32x4  __attribute__((ext_vector_type(4)));

// ---------------------------------------------------------------------------
template <int NW>
__device__ inline float block_reduce(float v, float* scratch) {
    #pragma unroll
    for (int off = 32; off > 0; off >>= 1) v += __shfl_down(v, off, 64);
    const int lane = threadIdx.x & 63, wid = threadIdx.x >> 6;
    if (lane == 0) scratch[wid] = v;
    __syncthreads();
    float s = 0.f;
    if (threadIdx.x == 0) {
        #pragma unroll
        for (int w = 0; w < NW; ++w) s += scratch[w];
    }
    return s;  // valid on thread 0 only
}

// Batcher odd-even 8-sort (19 CEs) — independent of running list (ILP).
#define CE_(A, i, j) { unsigned lo_ = min(A[i], A[j]); A[j] = max(A[i], A[j]); A[i] = lo_; }
__device__ inline void sort8(unsigned s[8]) {
    CE_(s,0,1) CE_(s,2,3) CE_(s,4,5) CE_(s,6,7)
    CE_(s,0,2) CE_(s,1,3) CE_(s,4,6) CE_(s,5,7)
    CE_(s,1,2) CE_(s,5,6)
    CE_(s,0,4) CE_(s,1,5) CE_(s,2,6) CE_(s,3,7)
    CE_(s,2,4) CE_(s,3,5)
    CE_(s,1,2) CE_(s,3,4) CE_(s,5,6)
}
// a (asc) := lowest-8 of union(a asc, s asc), sorted. Half-clean + bitonic merge.
__device__ inline void merge_top8(unsigned a[8], const unsigned s[8]) {
    #pragma unroll
    for (int i = 0; i < 8; ++i) a[i] = min(a[i], s[7 - i]);  // bitonic, lowest 8
    CE_(a,0,4) CE_(a,1,5) CE_(a,2,6) CE_(a,3,7)
    CE_(a,0,2) CE_(a,1,3) CE_(a,4,6) CE_(a,5,7)
    CE_(a,0,1) CE_(a,2,3) CE_(a,4,5) CE_(a,6,7)
}

// bf16 hi/lo split helpers (truncation; residual captures 8 more mantissa bits)
__device__ inline short hi16(float v) { return (short)(__float_as_uint(v) >> 16); }
__device__ inline float residual(float v) {
    return v - __uint_as_float(__float_as_uint(v) & 0xFFFF0000u);
}
__device__ inline unsigned pk2(short a, short b) {
    return (unsigned)(unsigned short)a | ((unsigned)(unsigned short)b << 16);
}
#define BF16_ONE ((short)0x3F80)

// ---------------------------------------------------------------------------
// Prep kernel: [0,320) convert all 20 clouds to A-frag format (once, not per
// consumer block — r11 recomputed this 16-64x redundantly); [320,352) pd+sp+tran,
// each block PLAIN-STORES its partial to a private slot (r12 bug: the ±1e30
// atomic offset trick lost the value to fp32 rounding — ulp(1e30)≈1.2e23).
// Unified frag format: f0 = (-2c hi/lo pairs, |c|^2 hi/lo), f1.w = (1,1):
// KNN pairs f1.w with B(k14/15)=|q|^2hi/lo; chamfer has B(k14/15)=0 -> no-op.
__global__ __launch_bounds__(256) void prep_kernel(const float* __restrict__ dp_all,
                                                   const float* __restrict__ src,
                                                   const float* __restrict__ tp,
                                                   const float* __restrict__ drp,
                                                   const float* __restrict__ pw,
                                                   const float* __restrict__ rm,
                                                   uint4* __restrict__ frag,
                                                   float* __restrict__ out) {
    if (blockIdx.x < NCONV_BLOCKS) {
        const int gid = blockIdx.x * 256 + threadIdx.x;  // 81920 candidates
        if (gid == 0) *out = 0.f;  // mega (next launch) atomicAdds into out
        const int c = gid >> 12;       // cloud 0..19
        const int j = gid & (N_ - 1);  // candidate in cloud
        const float* base = (c < 12) ? dp_all + (size_t)c * N_ * 3
                          : (c < 16) ? src + (size_t)(c - 12) * N_ * 3
                                     : tp + (size_t)(c - 16) * N_ * 3;
        float x = base[3 * j], y = base[3 * j + 1], z = base[3 * j + 2];
        float p2 = fmaf(x, x, fmaf(y, y, z * z));
        float mx = -2.f * x, my = -2.f * y, mz = -2.f * z;
        short mhx = hi16(mx), mhy = hi16(my), mhz = hi16(mz);
        short mlx = hi16(residual(mx)), mly = hi16(residual(my)), mlz = hi16(residual(mz));
        uint4 f0 = make_uint4(pk2(mhx, mhy), pk2(mhz, mlx), pk2(mly, mlz),
                              pk2(hi16(p2), hi16(residual(p2))));
        uint4 f1 = make_uint4(f0.x, f0.y, f0.z, pk2(BF16_ONE, BF16_ONE));
        const int w = j >> 9, jw = j & 511, tile = jw >> 4, m = jw & 15;
        size_t o = ((size_t)(c * NWIN + w)) * 1024 + tile * 32 + m;
        frag[o]      = f0;  // k0-7 slice
        frag[o + 16] = f1;  // k8-15 slice
    } else {  // ---- pd + sp + tran role
        __shared__ float red[4];
        const int PD_N = T_ * B_ * N_ * 3;
        const int SP_N = T_ * B_ * N_;
        const int stride = SL_BLOCKS * 256;
        const int gid = (blockIdx.x - NCONV_BLOCKS) * 256 + threadIdx.x;
        float apd = 0.f;
        for (int i = gid; i < PD_N; i += stride) {
            float d = drp[i] - dp_all[i];
            apd = fmaf(d, d, apd);
        }
        float asp = 0.f;
        for (int i = gid; i < SP_N; i += stride) asp += fabsf(pw[i]);
        float atr = 0.f;
        if (gid < T_ * B_ * 3) {
            int t = gid / (B_ * 3);
            int b = (gid / 3) % B_;
            int rr = gid % 3;
            float v = rm[t * B_ * 16 + b * 16 + rr * 4 + 3];
            atr = v * v;
        }
        float acc = apd * (1.0f / B_) + asp * (1.0f / (B_ * N_)) + atr * (1.0f / B_);
        float s = block_reduce<4>(acc, red);
        // One block per slot -> plain store, no init/atomic needed.
        if (threadIdx.x == 0)
            ((float*)&frag[20 * NWIN * 1024])[blockIdx.x - NCONV_BLOCKS] = s;
    }
}

// ---------------------------------------------------------------------------
// Mega kernel: 32 groups x (32 KNN + 12 chamfer) blocks. A-frags are copied
// (not computed) from the prefab cloud: 4 uint4 loads + 4 ds_write_b128 per
// thread per window, prefetched one window ahead (vmcnt overlaps compute).
__global__ __launch_bounds__(256, 6) void mega_kernel(const float* __restrict__ src,
                                                      const float* __restrict__ dp_all,
                                                      const float* __restrict__ tp,
                                                      const uint4* __restrict__ frag,
                                                      float* __restrict__ out) {
    __shared__ uint4 smem4[1024];  // 16 KiB
    const f32x4 zero4 = {0.f, 0.f, 0.f, 0.f};

    const int g = blockIdx.x / GRP_SZ;
    const int r = blockIdx.x % GRP_SZ;

    if (r < GRP_KNN) {  // ================= KNN + ARAP role (MFMA)
        const int knn_id = g * GRP_KNN + r;  // 0..1023
        uint4* alds = smem4;
        const int b   = knn_id / (N_ / 16);
        const int qt0 = (knn_id % (N_ / 16)) * 16;
        const float* sb = src + (size_t)b * N_ * 3;
        const uint4* fsrc = frag + ((size_t)(12 + b) * NWIN) * 1024;

        const int wid  = __builtin_amdgcn_readfirstlane(threadIdx.x >> 6);
        const int lane = threadIdx.x & 63;
        const int n    = lane & 15;
        const int quad = lane >> 4;
        const int rbase = quad * 4;
        const int qid  = qt0 + n;

        bf16x8 bfrag = (bf16x8)(short)0;
        {
            float x = sb[3 * qid], y = sb[3 * qid + 1], z = sb[3 * qid + 2];
            float q2 = fmaf(x, x, fmaf(y, y, z * z));
            short hx = hi16(x), hy = hi16(y), hz = hi16(z);
            short lx = hi16(residual(x)), ly = hi16(residual(y)), lz = hi16(residual(z));
            if (quad == 0) bfrag = (bf16x8){hx, hy, hz, hx, hy, hz, BF16_ONE, BF16_ONE};
            else if (quad == 1) bfrag = (bf16x8){lx, ly, lz, lx, ly, lz,
                                                 hi16(q2), hi16(residual(q2))};
        }

        unsigned a[K_];
        #pragma unroll
        for (int p = 0; p < K_; ++p) a[p] = 0xFFFFFFFFu;

        uint4 pf0 = fsrc[threadIdx.x],       pf1 = fsrc[256 + threadIdx.x],
              pf2 = fsrc[512 + threadIdx.x], pf3 = fsrc[768 + threadIdx.x];

        for (int w = 0; w < NWIN; ++w) {
            __syncthreads();  // previous window fully consumed
            alds[threadIdx.x]       = pf0;
            alds[256 + threadIdx.x] = pf1;
            alds[512 + threadIdx.x] = pf2;
            alds[768 + threadIdx.x] = pf3;
            __syncthreads();
            if (w + 1 < NWIN) {  // prefetch next window during compute
                const uint4* nf = fsrc + (size_t)(w + 1) * 1024;
                pf0 = nf[threadIdx.x];       pf1 = nf[256 + threadIdx.x];
                pf2 = nf[512 + threadIdx.x]; pf3 = nf[768 + threadIdx.x];
            }

            #pragma unroll
            for (int bt = 0; bt < 4; ++bt) {
                unsigned s8[8];
                #pragma unroll
                for (int h = 0; h < 2; ++h) {
                    const int tile = wid * 8 + bt * 2 + h;
                    const int tbg  = w * CWIN + tile * 16;
                    bf16x8 af = (bf16x8)(short)0;
                    if (quad < 2) {
                        union { uint4 u; bf16x8 v; } cv;
                        cv.u = alds[tile * 32 + quad * 16 + n];
                        af = cv.v;
                    }
                    f32x4 d = __builtin_amdgcn_mfma_f32_16x16x32_bf16(af, bfrag, zero4, 0, 0, 0);
                    #pragma unroll
                    for (int rr = 0; rr < 4; ++rr)
                        s8[h * 4 + rr] = (__float_as_uint(d[rr]) & 0xFFFFF000u)
                                         | (unsigned)(tbg | (rbase + rr));
                    if (tbg == qt0) {
                        #pragma unroll
                        for (int rr = 0; rr < 4; ++rr)
                            if (rbase + rr == n) s8[h * 4 + rr] = 0xFFFFFFFFu;
                    }
                }
                sort8(s8);
                merge_top8(a, s8);
            }
        }

        #pragma unroll
        for (int mk = 16; mk <= 32; mk <<= 1) {
            unsigned t[8];
            #pragma unroll
            for (int e = 0; e < K_; ++e) t[e] = __shfl_xor(a[e], mk, 64);
            merge_top8(a, t);
        }

        __syncthreads();
        unsigned* sm = (unsigned*)smem4;
        unsigned* nidx = (unsigned*)smem4 + 1024;
        if (lane < 16) {
            #pragma unroll
            for (int e = 0; e < K_; ++e) sm[(wid * 16 + n) * 9 + e] = a[e];
        }
        __syncthreads();
        if (threadIdx.x < 16) {
            const int q = threadIdx.x;
            unsigned md[K_];
            #pragma unroll
            for (int e = 0; e < K_; ++e) md[e] = sm[q * 9 + e];
            #pragma unroll
            for (int wv = 1; wv < 4; ++wv) {
                unsigned t[8];
                #pragma unroll
                for (int e = 0; e < K_; ++e) t[e] = sm[(wv * 16 + q) * 9 + e];
                merge_top8(md, t);
            }
            #pragma unroll
            for (int e = 0; e < K_; ++e) nidx[q * 8 + e] = md[e] & 0xFFFu;
        }
        __syncthreads();

        float acc = 0.f;
        if (threadIdx.x < 16 * K_) {
            const int q  = threadIdx.x >> 3;
            const int qi = qt0 + q;
            const int j  = (int)nidx[threadIdx.x];
            float sx = sb[3 * qi], sy = sb[3 * qi + 1], sz = sb[3 * qi + 2];
            float ex = sb[3 * j] - sx, ey = sb[3 * j + 1] - sy, ez = sb[3 * j + 2] - sz;
            float sd = sqrtf(fmaf(ex, ex, fmaf(ey, ey, ez * ez)) + 1e-5f);
            #pragma unroll
            for (int t = 0; t < T_; ++t) {
                const float* dpb = dp_all + ((size_t)(t * B_ + b)) * N_ * 3;
                float dx = dpb[3 * j] - dpb[3 * qi];
                float dy = dpb[3 * j + 1] - dpb[3 * qi + 1];
                float dz = dpb[3 * j + 2] - dpb[3 * qi + 2];
                float dd = sqrtf(fmaf(dx, dx, fmaf(dy, dy, dz * dz)) + 1e-5f);
                float df = dd - sd;
                acc = fmaf(df, df, acc);
            }
        }
        float s = block_reduce<4>(acc, (float*)smem4);
        if (threadIdx.x == 0) {
            float add = s * (1.0f / B_);
            if (blockIdx.x == 0) {  // fold in prep's small-loss partials
                const float* slp = (const float*)&frag[20 * NWIN * 1024];
                for (int i = 0; i < SL_BLOCKS; ++i) add += slp[i];
            }
            atomicAdd(out, add);
        }

    } else {  // ================= chamfer role (MFMA)
        const int cb = g * GRP_CH + (r - GRP_KNN);  // 0..383
        uint4* alds = smem4;
        const int tbd  = cb >> 4;
        const int slab = cb & 15;
        const int dir = tbd & 1;
        const int tb  = tbd >> 1;
        const int b = tb % B_, t = tb / B_;

        const float* dpb = dp_all + ((size_t)(t * B_ + b)) * N_ * 3;
        const float* tpb = tp + (size_t)b * N_ * 3;
        const float* qbase = dir ? tpb : dpb;  // queries
        const int ccloud = dir ? (t * B_ + b) : (16 + b);  // candidates
        const uint4* fsrc = frag + ((size_t)ccloud * NWIN) * 1024;

        const int lane = threadIdx.x & 63;
        const int wave = threadIdx.x >> 6;
        const int quad = lane >> 4;
        const int n    = lane & 15;

        bf16x8 bfrag[4];
        float  q2r[4];
        #pragma unroll
        for (int s = 0; s < 4; ++s) {
            int qid = slab * 256 + wave * 64 + s * 16 + n;
            float x = qbase[3 * qid], y = qbase[3 * qid + 1], z = qbase[3 * qid + 2];
            q2r[s] = fmaf(x, x, fmaf(y, y, z * z));
            short hx = hi16(x), hy = hi16(y), hz = hi16(z);
            short lx = hi16(residual(x)), ly = hi16(residual(y)), lz = hi16(residual(z));
            if (quad == 0)
                bfrag[s] = (bf16x8){hx, hy, hz, hx, hy, hz, BF16_ONE, BF16_ONE};
            else if (quad == 1)
                bfrag[s] = (bf16x8){lx, ly, lz, lx, ly, lz, 0, 0};  // k14/15=0: f1.w ones no-op
            else
                bfrag[s] = (bf16x8)(short)0;
        }

        float run[4] = {3.4e38f, 3.4e38f, 3.4e38f, 3.4e38f};

        uint4 pf0 = fsrc[threadIdx.x],       pf1 = fsrc[256 + threadIdx.x],
              pf2 = fsrc[512 + threadIdx.x], pf3 = fsrc[768 + threadIdx.x];

        for (int w = 0; w < NWIN; ++w) {
            __syncthreads();
            alds[threadIdx.x]       = pf0;
            alds[256 + threadIdx.x] = pf1;
            alds[512 + threadIdx.x] = pf2;
            alds[768 + threadIdx.x] = pf3;
            __syncthreads();
            if (w + 1 < NWIN) {
                const uint4* nf = fsrc + (size_t)(w + 1) * 1024;
                pf0 = nf[threadIdx.x];       pf1 = nf[256 + threadIdx.x];
                pf2 = nf[512 + threadIdx.x]; pf3 = nf[768 + threadIdx.x];
            }

            #pragma unroll 4
            for (int tile = 0; tile < CWIN / 16; ++tile) {
                bf16x8 af = (bf16x8)(short)0;
                if (quad < 2) {
                    union { uint4 u; bf16x8 v; } cv;
                    cv.u = alds[tile * 32 + quad * 16 + n];
                    af = cv.v;
                }
                #pragma unroll
                for (int s = 0; s < 4; ++s) {
                    f32x4 d = __builtin_amdgcn_mfma_f32_16x16x32_bf16(af, bfrag[s], zero4, 0, 0, 0);
                    float r3 = fminf(fminf(d[0], d[1]), d[2]);
                    run[s] = fminf(fminf(run[s], r3), d[3]);
                }
            }
        }

        float vsum = 0.f;
        #pragma unroll
        for (int s = 0; s < 4; ++s) {
            float rr = run[s];
            rr = fminf(rr, __shfl_xor(rr, 32));
            rr = fminf(rr, __shfl_xor(rr, 16));
            if (lane < 16) vsum += rr + q2r[s];
        }
        __syncthreads();
        float ssum = block_reduce<4>(vsum, (float*)smem4);
        if (threadIdx.x == 0) atomicAdd(out, ssum * (0.5f / B_));
    }
}

// ---------------------------------------------------------------------------
extern "C" void kernel_launch(void* const* d_in, const int* in_sizes, int n_in,
                              void* d_out, int out_size, void* d_ws, size_t ws_size,
                              hipStream_t stream) {
    const float* pw  = (const float*)d_in[1];
    const float* drp = (const float*)d_in[2];
    const float* dp  = (const float*)d_in[3];
    const float* rm  = (const float*)d_in[4];
    const float* sp  = (const float*)d_in[5];
    const float* tp  = (const float*)d_in[6];
    float* out = (float*)d_out;
    uint4* frag = (uint4*)d_ws;  // 20 clouds * 8192 uint4 = 2.56 MiB + 32-float SL scratch

    prep_kernel<<<NCONV_BLOCKS + SL_BLOCKS, 256, 0, stream>>>(dp, sp, tp, drp, pw, rm, frag, out);
    mega_kernel<<<GROUPS * GRP_SZ, 256, 0, stream>>>(sp, dp, tp, frag, out);
}

// Round 14
// 130.360 us; speedup vs baseline: 1.0399x; 1.0399x over previous
//
#include <hip/hip_runtime.h>

#define T_ 3
#define B_ 4
#define N_ 4096
#define K_ 8

// Mega: 32 groups of 89 blocks = 64 KNN + 24 chamfer + 1 SL.
// KNN block = 16 queries x half the candidates (4 of 8 windows);
// chamfer block = 256-query slab x half the candidates. Blocks are short and
// near-uniform -> even CU packing (r11 stalled at 31% occupancy with 5.5
// long uneven blocks/CU). Partials go to d_ws (plain stores, unique slots).
#define GROUPS 32
#define GRP_KNN 64
#define GRP_CH  24
#define GRP_SZ  89   // 64 + 24 + 1
#define SL_BLOCKS 32
#define CWIN 512

typedef short bf16x8 __attribute__((ext_vector_type(8)));
typedef float f32x4  __attribute__((ext_vector_type(4)));

// ---------------------------------------------------------------------------
template <int NW>
__device__ inline float block_reduce(float v, float* scratch) {
    #pragma unroll
    for (int off = 32; off > 0; off >>= 1) v += __shfl_down(v, off, 64);
    const int lane = threadIdx.x & 63, wid = threadIdx.x >> 6;
    if (lane == 0) scratch[wid] = v;
    __syncthreads();
    float s = 0.f;
    if (threadIdx.x == 0) {
        #pragma unroll
        for (int w = 0; w < NW; ++w) s += scratch[w];
    }
    return s;  // valid on thread 0 only
}

// Batcher odd-even 8-sort (19 CEs) — independent of running list (ILP).
#define CE_(A, i, j) { unsigned lo_ = min(A[i], A[j]); A[j] = max(A[i], A[j]); A[i] = lo_; }
__device__ inline void sort8(unsigned s[8]) {
    CE_(s,0,1) CE_(s,2,3) CE_(s,4,5) CE_(s,6,7)
    CE_(s,0,2) CE_(s,1,3) CE_(s,4,6) CE_(s,5,7)
    CE_(s,1,2) CE_(s,5,6)
    CE_(s,0,4) CE_(s,1,5) CE_(s,2,6) CE_(s,3,7)
    CE_(s,2,4) CE_(s,3,5)
    CE_(s,1,2) CE_(s,3,4) CE_(s,5,6)
}
// a (asc) := lowest-8 of union(a asc, s asc), sorted. Half-clean + bitonic merge.
__device__ inline void merge_top8(unsigned a[8], const unsigned s[8]) {
    #pragma unroll
    for (int i = 0; i < 8; ++i) a[i] = min(a[i], s[7 - i]);  // bitonic, lowest 8
    CE_(a,0,4) CE_(a,1,5) CE_(a,2,6) CE_(a,3,7)
    CE_(a,0,2) CE_(a,1,3) CE_(a,4,6) CE_(a,5,7)
    CE_(a,0,1) CE_(a,2,3) CE_(a,4,5) CE_(a,6,7)
}

// bf16 hi/lo split helpers (truncation; residual captures 8 more mantissa bits)
__device__ inline short hi16(float v) { return (short)(__float_as_uint(v) >> 16); }
__device__ inline float residual(float v) {
    return v - __uint_as_float(__float_as_uint(v) & 0xFFFF0000u);
}
__device__ inline unsigned pk2(short a, short b) {
    return (unsigned)(unsigned short)a | ((unsigned)(unsigned short)b << 16);
}
#define BF16_ONE ((short)0x3F80)

// ---------------------------------------------------------------------------
// Mega kernel. KNN/chamfer math identical to r11 (verified); candidates are
// converted locally from the raw cloud (r13's prefab tripled HBM traffic and
// regressed). KNN(+half) emits per-query packed sorted top-8 lists to knnp;
// chamfer(+half) emits per-query relative mins to chp; SL partials to slp.
// Block 0 zeroes *out for the finalize dispatch (stream-ordered).
__global__ __launch_bounds__(256, 6) void mega_kernel(const float* __restrict__ src,
                                                      const float* __restrict__ dp_all,
                                                      const float* __restrict__ tp,
                                                      const float* __restrict__ drp,
                                                      const float* __restrict__ pw,
                                                      const float* __restrict__ rm,
                                                      unsigned* __restrict__ knnp,
                                                      float* __restrict__ chp,
                                                      float* __restrict__ slp,
                                                      float* __restrict__ out) {
    __shared__ uint4 smem4[1024];  // 16 KiB
    const f32x4 zero4 = {0.f, 0.f, 0.f, 0.f};

    if (blockIdx.x == 0 && threadIdx.x == 0) *out = 0.f;

    const int g = blockIdx.x / GRP_SZ;
    const int r = blockIdx.x % GRP_SZ;

    if (r < GRP_KNN) {  // ================= KNN role (MFMA), half candidates
        const int knn_id = g * GRP_KNN + r;  // 0..2047
        const int half = knn_id & 1;
        const int kid2 = knn_id >> 1;        // 0..1023
        uint4* alds = smem4;
        const int b   = kid2 / (N_ / 16);
        const int qt0 = (kid2 % (N_ / 16)) * 16;
        const float* sb = src + (size_t)b * N_ * 3;

        const int wid  = __builtin_amdgcn_readfirstlane(threadIdx.x >> 6);
        const int lane = threadIdx.x & 63;
        const int n    = lane & 15;
        const int quad = lane >> 4;
        const int rbase = quad * 4;
        const int qid  = qt0 + n;

        bf16x8 bfrag = (bf16x8)(short)0;
        {
            float x = sb[3 * qid], y = sb[3 * qid + 1], z = sb[3 * qid + 2];
            float q2 = fmaf(x, x, fmaf(y, y, z * z));
            short hx = hi16(x), hy = hi16(y), hz = hi16(z);
            short lx = hi16(residual(x)), ly = hi16(residual(y)), lz = hi16(residual(z));
            if (quad == 0) bfrag = (bf16x8){hx, hy, hz, hx, hy, hz, BF16_ONE, BF16_ONE};
            else if (quad == 1) bfrag = (bf16x8){lx, ly, lz, lx, ly, lz,
                                                 hi16(q2), hi16(residual(q2))};
        }

        unsigned a[K_];
        #pragma unroll
        for (int p = 0; p < K_; ++p) a[p] = 0xFFFFFFFFu;

        for (int w = half * 4; w < half * 4 + 4; ++w) {  // this half's windows
            __syncthreads();
            #pragma unroll
            for (int rr = 0; rr < 2; ++rr) {
                int jloc = rr * 256 + threadIdx.x;
                int jg = w * CWIN + jloc;
                float x = sb[3 * jg], y = sb[3 * jg + 1], z = sb[3 * jg + 2];
                float p2 = fmaf(x, x, fmaf(y, y, z * z));
                float mx = -2.f * x, my = -2.f * y, mz = -2.f * z;
                short mhx = hi16(mx), mhy = hi16(my), mhz = hi16(mz);
                short mlx = hi16(residual(mx)), mly = hi16(residual(my)), mlz = hi16(residual(mz));
                uint4 f0 = make_uint4(pk2(mhx, mhy), pk2(mhz, mlx), pk2(mly, mlz),
                                      pk2(hi16(p2), hi16(residual(p2))));
                uint4 f1 = make_uint4(f0.x, f0.y, f0.z, pk2(BF16_ONE, BF16_ONE));
                int tile = jloc >> 4, m = jloc & 15;
                alds[tile * 32 + m]      = f0;
                alds[tile * 32 + 16 + m] = f1;
            }
            __syncthreads();

            #pragma unroll
            for (int bt = 0; bt < 4; ++bt) {
                unsigned s8[8];
                #pragma unroll
                for (int h = 0; h < 2; ++h) {
                    const int tile = wid * 8 + bt * 2 + h;
                    const int tbg  = w * CWIN + tile * 16;
                    bf16x8 af = (bf16x8)(short)0;
                    if (quad < 2) {
                        union { uint4 u; bf16x8 v; } cv;
                        cv.u = alds[tile * 32 + quad * 16 + n];
                        af = cv.v;
                    }
                    f32x4 d = __builtin_amdgcn_mfma_f32_16x16x32_bf16(af, bfrag, zero4, 0, 0, 0);
                    #pragma unroll
                    for (int rr = 0; rr < 4; ++rr)
                        s8[h * 4 + rr] = (__float_as_uint(d[rr]) & 0xFFFFF000u)
                                         | (unsigned)(tbg | (rbase + rr));
                    if (tbg == qt0) {  // self tile appears only in its own half
                        #pragma unroll
                        for (int rr = 0; rr < 4; ++rr)
                            if (rbase + rr == n) s8[h * 4 + rr] = 0xFFFFFFFFu;
                    }
                }
                sort8(s8);
                merge_top8(a, s8);
            }
        }

        #pragma unroll
        for (int mk = 16; mk <= 32; mk <<= 1) {
            unsigned t[8];
            #pragma unroll
            for (int e = 0; e < K_; ++e) t[e] = __shfl_xor(a[e], mk, 64);
            merge_top8(a, t);
        }

        __syncthreads();
        unsigned* sm = (unsigned*)smem4;
        if (lane < 16) {
            #pragma unroll
            for (int e = 0; e < K_; ++e) sm[(wid * 16 + n) * 9 + e] = a[e];
        }
        __syncthreads();
        if (threadIdx.x < 16) {
            const int q = threadIdx.x;
            unsigned md[K_];
            #pragma unroll
            for (int e = 0; e < K_; ++e) md[e] = sm[q * 9 + e];
            #pragma unroll
            for (int wv = 1; wv < 4; ++wv) {
                unsigned t[8];
                #pragma unroll
                for (int e = 0; e < K_; ++e) t[e] = sm[(wv * 16 + q) * 9 + e];
                merge_top8(md, t);
            }
            // Store this half's sorted top-8 (packed) for the finalize merge.
            unsigned* dst = knnp + ((size_t)(b * N_ + qt0 + q) * 2 + half) * 8;
            #pragma unroll
            for (int e = 0; e < K_; ++e) dst[e] = md[e];
        }

    } else if (r < GRP_KNN + GRP_CH) {  // ========= chamfer role, half candidates
        const int cb = g * GRP_CH + (r - GRP_KNN);  // 0..767
        const int half = cb & 1;
        const int rest = cb >> 1;     // 0..383
        uint4* alds = smem4;
        const int tbd  = rest >> 4;   // ((t*B+b)*2+dir)
        const int slab = rest & 15;
        const int dir = tbd & 1;
        const int tb  = tbd >> 1;
        const int b = tb % B_, t = tb / B_;

        const float* dpb = dp_all + ((size_t)(t * B_ + b)) * N_ * 3;
        const float* tpb = tp + (size_t)b * N_ * 3;
        const float* cbase = dir ? dpb : tpb;  // candidates
        const float* qbase = dir ? tpb : dpb;  // queries

        const int lane = threadIdx.x & 63;
        const int wave = threadIdx.x >> 6;
        const int quad = lane >> 4;
        const int n    = lane & 15;

        bf16x8 bfrag[4];
        #pragma unroll
        for (int s = 0; s < 4; ++s) {
            int qid = slab * 256 + wave * 64 + s * 16 + n;
            float x = qbase[3 * qid], y = qbase[3 * qid + 1], z = qbase[3 * qid + 2];
            short hx = hi16(x), hy = hi16(y), hz = hi16(z);
            short lx = hi16(residual(x)), ly = hi16(residual(y)), lz = hi16(residual(z));
            if (quad == 0)
                bfrag[s] = (bf16x8){hx, hy, hz, hx, hy, hz, BF16_ONE, BF16_ONE};
            else if (quad == 1)
                bfrag[s] = (bf16x8){lx, ly, lz, lx, ly, lz, 0, 0};
            else
                bfrag[s] = (bf16x8)(short)0;
        }

        float run[4] = {3.4e38f, 3.4e38f, 3.4e38f, 3.4e38f};

        for (int w = half * 4; w < half * 4 + 4; ++w) {
            __syncthreads();
            #pragma unroll
            for (int rr = 0; rr < 2; ++rr) {
                int jloc = rr * 256 + threadIdx.x;
                int jg = w * CWIN + jloc;
                float x = cbase[3 * jg], y = cbase[3 * jg + 1], z = cbase[3 * jg + 2];
                float p2 = fmaf(x, x, fmaf(y, y, z * z));
                float mx = -2.f * x, my = -2.f * y, mz = -2.f * z;
                short mhx = hi16(mx), mhy = hi16(my), mhz = hi16(mz);
                short mlx = hi16(residual(mx)), mly = hi16(residual(my)), mlz = hi16(residual(mz));
                uint4 f0 = make_uint4(pk2(mhx, mhy), pk2(mhz, mlx), pk2(mly, mlz),
                                      pk2(hi16(p2), hi16(residual(p2))));
                uint4 f1 = make_uint4(f0.x, f0.y, f0.z, 0u);
                int tile = jloc >> 4, m = jloc & 15;
                alds[tile * 32 + m]      = f0;
                alds[tile * 32 + 16 + m] = f1;
            }
            __syncthreads();

            #pragma unroll 4
            for (int tile = 0; tile < CWIN / 16; ++tile) {
                bf16x8 af = (bf16x8)(short)0;
                if (quad < 2) {
                    union { uint4 u; bf16x8 v; } cv;
                    cv.u = alds[tile * 32 + quad * 16 + n];
                    af = cv.v;
                }
                #pragma unroll
                for (int s = 0; s < 4; ++s) {
                    f32x4 d = __builtin_amdgcn_mfma_f32_16x16x32_bf16(af, bfrag[s], zero4, 0, 0, 0);
                    float r3 = fminf(fminf(d[0], d[1]), d[2]);
                    run[s] = fminf(fminf(run[s], r3), d[3]);
                }
            }
        }

        // Per-query relative min for this half -> chp (unique slot, plain store).
        #pragma unroll
        for (int s = 0; s < 4; ++s) {
            float rr = run[s];
            rr = fminf(rr, __shfl_xor(rr, 32));
            rr = fminf(rr, __shfl_xor(rr, 16));
            if (lane < 16) {
                int qid = slab * 256 + wave * 64 + s * 16 + n;
                chp[((size_t)(tbd * 2 + half)) * N_ + qid] = rr;
            }
        }

    } else {  // ================= pd + sp + tran role (SL)
        __shared__ float red[4];
        const int PD_N = T_ * B_ * N_ * 3;
        const int SP_N = T_ * B_ * N_;
        const int stride = SL_BLOCKS * 256;
        const int gid = g * 256 + threadIdx.x;
        float apd = 0.f;
        for (int i = gid; i < PD_N; i += stride) {
            float d = drp[i] - dp_all[i];
            apd = fmaf(d, d, apd);
        }
        float asp = 0.f;
        for (int i = gid; i < SP_N; i += stride) asp += fabsf(pw[i]);
        float atr = 0.f;
        if (gid < T_ * B_ * 3) {
            int t = gid / (B_ * 3);
            int b = (gid / 3) % B_;
            int rr = gid % 3;
            float v = rm[t * B_ * 16 + b * 16 + rr * 4 + 3];
            atr = v * v;
        }
        float acc = apd * (1.0f / B_) + asp * (1.0f / (B_ * N_)) + atr * (1.0f / B_);
        float s = block_reduce<4>(acc, red);
        if (threadIdx.x == 0) slp[g] = s;  // unique slot, plain store
    }
}

// ---------------------------------------------------------------------------
// Finalize: [0,384) chamfer merge (min of 2 halves + |q|^2, reduce);
// [384,896) knn merge + ARAP (32 queries/block, thread = (query,k));
// [896] SL partial fold. All atomicAdd into out (zeroed by mega block 0).
__global__ __launch_bounds__(256) void finalize_kernel(const float* __restrict__ src,
                                                       const float* __restrict__ dp_all,
                                                       const float* __restrict__ tp,
                                                       const unsigned* __restrict__ knnp,
                                                       const float* __restrict__ chp,
                                                       const float* __restrict__ slp,
                                                       float* __restrict__ out) {
    __shared__ float red[4];
    const int blk = blockIdx.x;

    if (blk < 384) {  // ---- chamfer merge
        const int tbd = blk >> 4;
        const int q = (blk & 15) * 256 + threadIdx.x;
        const int dir = tbd & 1, tb = tbd >> 1, b = tb % B_, t = tb / B_;
        const float* qbase = dir ? tp + (size_t)b * N_ * 3
                                 : dp_all + ((size_t)(t * B_ + b)) * N_ * 3;
        float m = fminf(chp[(size_t)(tbd * 2) * N_ + q],
                        chp[(size_t)(tbd * 2 + 1) * N_ + q]);
        float x = qbase[3 * q], y = qbase[3 * q + 1], z = qbase[3 * q + 2];
        float v = fmaf(x, x, fmaf(y, y, z * z)) + m;
        float s = block_reduce<4>(v, red);
        if (threadIdx.x == 0) atomicAdd(out, s * (0.5f / B_));
    } else if (blk < 896) {  // ---- knn merge + ARAP
        const int qb = (blk - 384) * 32;
        const int ql = threadIdx.x >> 3;     // 0..31
        const int k  = threadIdx.x & 7;
        const int qglob = qb + ql;           // 0..16383
        const int b  = qglob >> 12;
        const int qi = qglob & (N_ - 1);
        // Merge the two halves' sorted-8 lists (redundant across the 8 k-threads,
        // 32 cheap ops vs the gathers below).
        const unsigned* p0 = knnp + (size_t)qglob * 16;
        unsigned a[K_], s2[K_];
        #pragma unroll
        for (int e = 0; e < K_; ++e) { a[e] = p0[e]; s2[e] = p0[8 + e]; }
        merge_top8(a, s2);
        const int j = (int)(a[k] & 0xFFFu);

        const float* sb = src + (size_t)b * N_ * 3;
        float sx = sb[3 * qi], sy = sb[3 * qi + 1], sz = sb[3 * qi + 2];
        float ex = sb[3 * j] - sx, ey = sb[3 * j + 1] - sy, ez = sb[3 * j + 2] - sz;
        float sd = sqrtf(fmaf(ex, ex, fmaf(ey, ey, ez * ez)) + 1e-5f);
        float acc = 0.f;
        #pragma unroll
        for (int t = 0; t < T_; ++t) {
            const float* dpb = dp_all + ((size_t)(t * B_ + b)) * N_ * 3;
            float dx = dpb[3 * j] - dpb[3 * qi];
            float dy = dpb[3 * j + 1] - dpb[3 * qi + 1];
            float dz = dpb[3 * j + 2] - dpb[3 * qi + 2];
            float dd = sqrtf(fmaf(dx, dx, fmaf(dy, dy, dz * dz)) + 1e-5f);
            float df = dd - sd;
            acc = fmaf(df, df, acc);
        }
        float s = block_reduce<4>(acc, red);
        if (threadIdx.x == 0) atomicAdd(out, s * (1.0f / B_));
    } else {  // ---- SL fold
        float v = (threadIdx.x < SL_BLOCKS) ? slp[threadIdx.x] : 0.f;
        float s = block_reduce<4>(v, red);
        if (threadIdx.x == 0) atomicAdd(out, s);
    }
}

// ---------------------------------------------------------------------------
extern "C" void kernel_launch(void* const* d_in, const int* in_sizes, int n_in,
                              void* d_out, int out_size, void* d_ws, size_t ws_size,
                              hipStream_t stream) {
    const float* pw  = (const float*)d_in[1];
    const float* drp = (const float*)d_in[2];
    const float* dp  = (const float*)d_in[3];
    const float* rm  = (const float*)d_in[4];
    const float* sp  = (const float*)d_in[5];
    const float* tp  = (const float*)d_in[6];
    float* out = (float*)d_out;

    unsigned* knnp = (unsigned*)d_ws;                         // 16384*2*8 u32 = 1 MiB
    float*    chp  = (float*)((char*)d_ws + (1u << 20));      // 24*2*4096 f32 = 768 KiB
    float*    slp  = (float*)((char*)d_ws + (1u << 20) + 24 * 2 * N_ * 4);  // 32 f32

    mega_kernel<<<GROUPS * GRP_SZ, 256, 0, stream>>>(sp, dp, tp, drp, pw, rm,
                                                     knnp, chp, slp, out);
    finalize_kernel<<<897, 256, 0, stream>>>(sp, dp, tp, knnp, chp, slp, out);
}

// Round 15
// 127.069 us; speedup vs baseline: 1.0668x; 1.0259x over previous
//
#include <hip/hip_runtime.h>

#define T_ 3
#define B_ 4
#define N_ 4096
#define K_ 8

// Role interleave (r11): 32 groups of 45 blocks = 32 KNN + 12 chamfer + 1 SL.
#define GROUPS 32
#define GRP_KNN 32
#define GRP_CH  12
#define GRP_SZ  45
#define CWIN 512
#define NWIN (N_ / CWIN)  // 8

typedef short bf16x8 __attribute__((ext_vector_type(8)));
typedef float f32x4  __attribute__((ext_vector_type(4)));

// ---------------------------------------------------------------------------
template <int NW>
__device__ inline float block_reduce(float v, float* scratch) {
    #pragma unroll
    for (int off = 32; off > 0; off >>= 1) v += __shfl_down(v, off, 64);
    const int lane = threadIdx.x & 63, wid = threadIdx.x >> 6;
    if (lane == 0) scratch[wid] = v;
    __syncthreads();
    float s = 0.f;
    if (threadIdx.x == 0) {
        #pragma unroll
        for (int w = 0; w < NW; ++w) s += scratch[w];
    }
    return s;  // valid on thread 0 only
}

// Batcher odd-even 8-sort (19 CEs) — independent of running list (ILP).
#define CE_(A, i, j) { unsigned lo_ = min(A[i], A[j]); A[j] = max(A[i], A[j]); A[i] = lo_; }
__device__ inline void sort8(unsigned s[8]) {
    CE_(s,0,1) CE_(s,2,3) CE_(s,4,5) CE_(s,6,7)
    CE_(s,0,2) CE_(s,1,3) CE_(s,4,6) CE_(s,5,7)
    CE_(s,1,2) CE_(s,5,6)
    CE_(s,0,4) CE_(s,1,5) CE_(s,2,6) CE_(s,3,7)
    CE_(s,2,4) CE_(s,3,5)
    CE_(s,1,2) CE_(s,3,4) CE_(s,5,6)
}
// a (asc) := lowest-8 of union(a asc, s asc), sorted. Half-clean + bitonic merge.
__device__ inline void merge_top8(unsigned a[8], const unsigned s[8]) {
    #pragma unroll
    for (int i = 0; i < 8; ++i) a[i] = min(a[i], s[7 - i]);  // bitonic, lowest 8
    CE_(a,0,4) CE_(a,1,5) CE_(a,2,6) CE_(a,3,7)
    CE_(a,0,2) CE_(a,1,3) CE_(a,4,6) CE_(a,5,7)
    CE_(a,0,1) CE_(a,2,3) CE_(a,4,5) CE_(a,6,7)
}

// bf16 hi/lo split helpers (truncation; residual captures 8 more mantissa bits)
__device__ inline short hi16(float v) { return (short)(__float_as_uint(v) >> 16); }
__device__ inline float residual(float v) {
    return v - __uint_as_float(__float_as_uint(v) & 0xFFFF0000u);
}
__device__ inline unsigned pk2(short a, short b) {
    return (unsigned)(unsigned short)a | ((unsigned)(unsigned short)b << 16);
}
#define BF16_ONE ((short)0x3F80)

// Convert one candidate (x,y,z) to the two A-frag slices.
__device__ inline void conv_frag(float x, float y, float z, unsigned f1w,
                                 uint4& f0, uint4& f1) {
    float p2 = fmaf(x, x, fmaf(y, y, z * z));
    float mx = -2.f * x, my = -2.f * y, mz = -2.f * z;
    f0 = make_uint4(pk2(hi16(mx), hi16(my)),
                    pk2(hi16(mz), hi16(residual(mx))),
                    pk2(hi16(residual(my)), hi16(residual(mz))),
                    pk2(hi16(p2), hi16(residual(p2))));
    f1 = make_uint4(f0.x, f0.y, f0.z, f1w);
}

// ---------------------------------------------------------------------------
// Mega kernel (r11 structure — best verified) + register prefetch of the raw
// staging floats one window ahead: the global-load latency (~200-900 cyc) that
// sat inside every barrier-to-barrier window segment now overlaps the previous
// window's MFMA+selection compute. Roles: KNN+ARAP (MFMA distances, packed
// sortable top-8 selection), chamfer (MFMA + running min), pd+sp+tran.
__global__ __launch_bounds__(256, 6) void mega_kernel(const float* __restrict__ src,
                                                      const float* __restrict__ dp_all,
                                                      const float* __restrict__ tp,
                                                      const float* __restrict__ drp,
                                                      const float* __restrict__ pw,
                                                      const float* __restrict__ rm,
                                                      float* __restrict__ out) {
    __shared__ uint4 smem4[1024];  // 16 KiB
    const f32x4 zero4 = {0.f, 0.f, 0.f, 0.f};

    const int g = blockIdx.x / GRP_SZ;
    const int r = blockIdx.x % GRP_SZ;

    if (r < GRP_KNN) {  // ================= KNN + ARAP role (MFMA)
        const int knn_id = g * GRP_KNN + r;  // 0..1023
        uint4* alds = smem4;
        const int b   = knn_id / (N_ / 16);
        const int qt0 = (knn_id % (N_ / 16)) * 16;
        const float* sb = src + (size_t)b * N_ * 3;

        const int wid  = __builtin_amdgcn_readfirstlane(threadIdx.x >> 6);
        const int lane = threadIdx.x & 63;
        const int n    = lane & 15;
        const int quad = lane >> 4;
        const int rbase = quad * 4;
        const int qid  = qt0 + n;

        bf16x8 bfrag = (bf16x8)(short)0;
        {
            float x = sb[3 * qid], y = sb[3 * qid + 1], z = sb[3 * qid + 2];
            float q2 = fmaf(x, x, fmaf(y, y, z * z));
            short hx = hi16(x), hy = hi16(y), hz = hi16(z);
            short lx = hi16(residual(x)), ly = hi16(residual(y)), lz = hi16(residual(z));
            if (quad == 0) bfrag = (bf16x8){hx, hy, hz, hx, hy, hz, BF16_ONE, BF16_ONE};
            else if (quad == 1) bfrag = (bf16x8){lx, ly, lz, lx, ly, lz,
                                                 hi16(q2), hi16(residual(q2))};
        }

        unsigned a[K_];
        #pragma unroll
        for (int p = 0; p < K_; ++p) a[p] = 0xFFFFFFFFu;

        // Prefetched raw staging floats for candidates (tid) and (tid+256).
        float ax, ay, az, bx2, by2, bz2;
        {
            int j0 = threadIdx.x, j1 = threadIdx.x + 256;
            ax = sb[3 * j0]; ay = sb[3 * j0 + 1]; az = sb[3 * j0 + 2];
            bx2 = sb[3 * j1]; by2 = sb[3 * j1 + 1]; bz2 = sb[3 * j1 + 2];
        }

        for (int w = 0; w < NWIN; ++w) {
            __syncthreads();  // previous window consumed
            {
                uint4 f0, f1;
                int jloc = threadIdx.x, tile = jloc >> 4, m = jloc & 15;
                conv_frag(ax, ay, az, pk2(BF16_ONE, BF16_ONE), f0, f1);
                alds[tile * 32 + m] = f0;  alds[tile * 32 + 16 + m] = f1;
                jloc = threadIdx.x + 256; tile = jloc >> 4; m = jloc & 15;
                conv_frag(bx2, by2, bz2, pk2(BF16_ONE, BF16_ONE), f0, f1);
                alds[tile * 32 + m] = f0;  alds[tile * 32 + 16 + m] = f1;
            }
            __syncthreads();
            if (w + 1 < NWIN) {  // prefetch next window's raw floats
                int j0 = (w + 1) * CWIN + threadIdx.x, j1 = j0 + 256;
                ax = sb[3 * j0]; ay = sb[3 * j0 + 1]; az = sb[3 * j0 + 2];
                bx2 = sb[3 * j1]; by2 = sb[3 * j1 + 1]; bz2 = sb[3 * j1 + 2];
            }

            #pragma unroll
            for (int bt = 0; bt < 4; ++bt) {
                unsigned s8[8];
                #pragma unroll
                for (int h = 0; h < 2; ++h) {
                    const int tile = wid * 8 + bt * 2 + h;
                    const int tbg  = w * CWIN + tile * 16;
                    bf16x8 af = (bf16x8)(short)0;
                    if (quad < 2) {
                        union { uint4 u; bf16x8 v; } cv;
                        cv.u = alds[tile * 32 + quad * 16 + n];
                        af = cv.v;
                    }
                    f32x4 d = __builtin_amdgcn_mfma_f32_16x16x32_bf16(af, bfrag, zero4, 0, 0, 0);
                    #pragma unroll
                    for (int rr = 0; rr < 4; ++rr)
                        s8[h * 4 + rr] = (__float_as_uint(d[rr]) & 0xFFFFF000u)
                                         | (unsigned)(tbg | (rbase + rr));
                    if (tbg == qt0) {  // wave-uniform: the one self-overlap tile
                        #pragma unroll
                        for (int rr = 0; rr < 4; ++rr)
                            if (rbase + rr == n) s8[h * 4 + rr] = 0xFFFFFFFFu;
                    }
                }
                sort8(s8);
                merge_top8(a, s8);
            }
        }

        // Fold the 4 row-quads of each query column.
        #pragma unroll
        for (int mk = 16; mk <= 32; mk <<= 1) {
            unsigned t[8];
            #pragma unroll
            for (int e = 0; e < K_; ++e) t[e] = __shfl_xor(a[e], mk, 64);
            merge_top8(a, t);
        }

        // Cross-wave merge + publish indices.
        __syncthreads();
        unsigned* sm = (unsigned*)smem4;
        unsigned* nidx = (unsigned*)smem4 + 1024;
        if (lane < 16) {
            #pragma unroll
            for (int e = 0; e < K_; ++e) sm[(wid * 16 + n) * 9 + e] = a[e];
        }
        __syncthreads();
        if (threadIdx.x < 16) {
            const int q = threadIdx.x;
            unsigned md[K_];
            #pragma unroll
            for (int e = 0; e < K_; ++e) md[e] = sm[q * 9 + e];
            #pragma unroll
            for (int wv = 1; wv < 4; ++wv) {
                unsigned t[8];
                #pragma unroll
                for (int e = 0; e < K_; ++e) t[e] = sm[(wv * 16 + q) * 9 + e];
                merge_top8(md, t);
            }
            #pragma unroll
            for (int e = 0; e < K_; ++e) nidx[q * 8 + e] = md[e] & 0xFFFu;
        }
        __syncthreads();

        // Fused ARAP: 128 threads = 16 queries x 8 neighbors, all 3 t stages.
        float acc = 0.f;
        if (threadIdx.x < 16 * K_) {
            const int q  = threadIdx.x >> 3;
            const int qi = qt0 + q;
            const int j  = (int)nidx[threadIdx.x];
            float sx = sb[3 * qi], sy = sb[3 * qi + 1], sz = sb[3 * qi + 2];
            float ex = sb[3 * j] - sx, ey = sb[3 * j + 1] - sy, ez = sb[3 * j + 2] - sz;
            float sd = sqrtf(fmaf(ex, ex, fmaf(ey, ey, ez * ez)) + 1e-5f);
            #pragma unroll
            for (int t = 0; t < T_; ++t) {
                const float* dpb = dp_all + ((size_t)(t * B_ + b)) * N_ * 3;
                float dx = dpb[3 * j] - dpb[3 * qi];
                float dy = dpb[3 * j + 1] - dpb[3 * qi + 1];
                float dz = dpb[3 * j + 2] - dpb[3 * qi + 2];
                float dd = sqrtf(fmaf(dx, dx, fmaf(dy, dy, dz * dz)) + 1e-5f);
                float df = dd - sd;
                acc = fmaf(df, df, acc);
            }
        }
        float s = block_reduce<4>(acc, (float*)smem4);
        if (threadIdx.x == 0) atomicAdd(out, s * (1.0f / B_));

    } else if (r < GRP_KNN + GRP_CH) {  // ================= chamfer role (MFMA)
        const int cb = g * GRP_CH + (r - GRP_KNN);  // 0..383
        uint4* alds = smem4;
        const int tbd  = cb >> 4;
        const int slab = cb & 15;
        const int dir = tbd & 1;
        const int tb  = tbd >> 1;
        const int b = tb % B_, t = tb / B_;

        const float* dpb = dp_all + ((size_t)(t * B_ + b)) * N_ * 3;
        const float* tpb = tp + (size_t)b * N_ * 3;
        const float* cbase = dir ? dpb : tpb;  // candidates
        const float* qbase = dir ? tpb : dpb;  // queries

        const int lane = threadIdx.x & 63;
        const int wave = threadIdx.x >> 6;
        const int quad = lane >> 4;
        const int n    = lane & 15;

        bf16x8 bfrag[4];
        float  q2r[4];
        #pragma unroll
        for (int s = 0; s < 4; ++s) {
            int qid = slab * 256 + wave * 64 + s * 16 + n;
            float x = qbase[3 * qid], y = qbase[3 * qid + 1], z = qbase[3 * qid + 2];
            q2r[s] = fmaf(x, x, fmaf(y, y, z * z));
            short hx = hi16(x), hy = hi16(y), hz = hi16(z);
            short lx = hi16(residual(x)), ly = hi16(residual(y)), lz = hi16(residual(z));
            if (quad == 0)
                bfrag[s] = (bf16x8){hx, hy, hz, hx, hy, hz, BF16_ONE, BF16_ONE};
            else if (quad == 1)
                bfrag[s] = (bf16x8){lx, ly, lz, lx, ly, lz, 0, 0};  // k14/15=0: f1.w ones no-op
            else
                bfrag[s] = (bf16x8)(short)0;
        }

        float run[4] = {3.4e38f, 3.4e38f, 3.4e38f, 3.4e38f};

        float ax, ay, az, bx2, by2, bz2;
        {
            int j0 = threadIdx.x, j1 = threadIdx.x + 256;
            ax = cbase[3 * j0]; ay = cbase[3 * j0 + 1]; az = cbase[3 * j0 + 2];
            bx2 = cbase[3 * j1]; by2 = cbase[3 * j1 + 1]; bz2 = cbase[3 * j1 + 2];
        }

        for (int w = 0; w < NWIN; ++w) {
            __syncthreads();
            {
                uint4 f0, f1;
                int jloc = threadIdx.x, tile = jloc >> 4, m = jloc & 15;
                conv_frag(ax, ay, az, pk2(BF16_ONE, BF16_ONE), f0, f1);
                alds[tile * 32 + m] = f0;  alds[tile * 32 + 16 + m] = f1;
                jloc = threadIdx.x + 256; tile = jloc >> 4; m = jloc & 15;
                conv_frag(bx2, by2, bz2, pk2(BF16_ONE, BF16_ONE), f0, f1);
                alds[tile * 32 + m] = f0;  alds[tile * 32 + 16 + m] = f1;
            }
            __syncthreads();
            if (w + 1 < NWIN) {
                int j0 = (w + 1) * CWIN + threadIdx.x, j1 = j0 + 256;
                ax = cbase[3 * j0]; ay = cbase[3 * j0 + 1]; az = cbase[3 * j0 + 2];
                bx2 = cbase[3 * j1]; by2 = cbase[3 * j1 + 1]; bz2 = cbase[3 * j1 + 2];
            }

            #pragma unroll 4
            for (int tile = 0; tile < CWIN / 16; ++tile) {
                bf16x8 af = (bf16x8)(short)0;
                if (quad < 2) {
                    union { uint4 u; bf16x8 v; } cv;
                    cv.u = alds[tile * 32 + quad * 16 + n];
                    af = cv.v;
                }
                #pragma unroll
                for (int s = 0; s < 4; ++s) {
                    f32x4 d = __builtin_amdgcn_mfma_f32_16x16x32_bf16(af, bfrag[s], zero4, 0, 0, 0);
                    float r3 = fminf(fminf(d[0], d[1]), d[2]);
                    run[s] = fminf(fminf(run[s], r3), d[3]);
                }
            }
        }

        float vsum = 0.f;
        #pragma unroll
        for (int s = 0; s < 4; ++s) {
            float rr = run[s];
            rr = fminf(rr, __shfl_xor(rr, 32));
            rr = fminf(rr, __shfl_xor(rr, 16));
            if (lane < 16) vsum += rr + q2r[s];
        }
        __syncthreads();
        float ssum = block_reduce<4>(vsum, (float*)smem4);
        if (threadIdx.x == 0) atomicAdd(out, ssum * (0.5f / B_));

    } else {  // ================= pd + sp + tran role
        const int PD_N = T_ * B_ * N_ * 3;
        const int SP_N = T_ * B_ * N_;
        const int stride = GROUPS * 256;
        const int gid = g * 256 + threadIdx.x;
        float apd = 0.f;
        for (int i = gid; i < PD_N; i += stride) {
            float d = drp[i] - dp_all[i];
            apd = fmaf(d, d, apd);
        }
        float asp = 0.f;
        for (int i = gid; i < SP_N; i += stride) asp += fabsf(pw[i]);
        float atr = 0.f;
        if (gid < T_ * B_ * 3) {
            int t = gid / (B_ * 3);
            int b = (gid / 3) % B_;
            int rr = gid % 3;
            float v = rm[t * B_ * 16 + b * 16 + rr * 4 + 3];
            atr = v * v;
        }
        float acc = apd * (1.0f / B_) + asp * (1.0f / (B_ * N_)) + atr * (1.0f / B_);
        float s = block_reduce<4>(acc, (float*)smem4);
        if (threadIdx.x == 0) atomicAdd(out, s);
    }
}

// ---------------------------------------------------------------------------
extern "C" void kernel_launch(void* const* d_in, const int* in_sizes, int n_in,
                              void* d_out, int out_size, void* d_ws, size_t ws_size,
                              hipStream_t stream) {
    const float* pw  = (const float*)d_in[1];
    const float* drp = (const float*)d_in[2];
    const float* dp  = (const float*)d_in[3];
    const float* rm  = (const float*)d_in[4];
    const float* sp  = (const float*)d_in[5];
    const float* tp  = (const float*)d_in[6];
    float* out = (float*)d_out;

    hipMemsetAsync(out, 0, sizeof(float), stream);
    mega_kernel<<<GROUPS * GRP_SZ, 256, 0, stream>>>(sp, dp, tp, drp, pw, rm, out);
}

// Round 16
// 125.825 us; speedup vs baseline: 1.0774x; 1.0099x over previous
//
#include <hip/hip_runtime.h>

#define T_ 3
#define B_ 4
#define N_ 4096
#define K_ 8

// Mega interleave: 32 groups of 44 blocks = 32 KNN + 12 chamfer (SL -> prep).
#define GROUPS 32
#define GRP_KNN 32
#define GRP_CH  12
#define GRP_SZ  44
#define NCHUNK 16      // 16 chunks of 256 candidates
#define SL_BLOCKS 32

typedef short bf16x8 __attribute__((ext_vector_type(8)));
typedef float f32x4  __attribute__((ext_vector_type(4)));

// ---------------------------------------------------------------------------
template <int NW>
__device__ inline float block_reduce(float v, float* scratch) {
    #pragma unroll
    for (int off = 32; off > 0; off >>= 1) v += __shfl_down(v, off, 64);
    const int lane = threadIdx.x & 63, wid = threadIdx.x >> 6;
    if (lane == 0) scratch[wid] = v;
    __syncthreads();
    float s = 0.f;
    if (threadIdx.x == 0) {
        #pragma unroll
        for (int w = 0; w < NW; ++w) s += scratch[w];
    }
    return s;  // valid on thread 0 only
}

#define CE_(A, i, j) { unsigned lo_ = min(A[i], A[j]); A[j] = max(A[i], A[j]); A[i] = lo_; }
__device__ inline void sort8(unsigned s[8]) {
    CE_(s,0,1) CE_(s,2,3) CE_(s,4,5) CE_(s,6,7)
    CE_(s,0,2) CE_(s,1,3) CE_(s,4,6) CE_(s,5,7)
    CE_(s,1,2) CE_(s,5,6)
    CE_(s,0,4) CE_(s,1,5) CE_(s,2,6) CE_(s,3,7)
    CE_(s,2,4) CE_(s,3,5)
    CE_(s,1,2) CE_(s,3,4) CE_(s,5,6)
}
__device__ inline void merge_top8(unsigned a[8], const unsigned s[8]) {
    #pragma unroll
    for (int i = 0; i < 8; ++i) a[i] = min(a[i], s[7 - i]);
    CE_(a,0,4) CE_(a,1,5) CE_(a,2,6) CE_(a,3,7)
    CE_(a,0,2) CE_(a,1,3) CE_(a,4,6) CE_(a,5,7)
    CE_(a,0,1) CE_(a,2,3) CE_(a,4,5) CE_(a,6,7)
}

__device__ inline short hi16(float v) { return (short)(__float_as_uint(v) >> 16); }
__device__ inline float residual(float v) {
    return v - __uint_as_float(__float_as_uint(v) & 0xFFFF0000u);
}
__device__ inline unsigned pk2(short a, short b) {
    return (unsigned)(unsigned short)a | ((unsigned)(unsigned short)b << 16);
}
#define BF16_ONE ((short)0x3F80)

__device__ inline void conv_frag(float x, float y, float z, unsigned f1w,
                                 uint4& f0, uint4& f1) {
    float p2 = fmaf(x, x, fmaf(y, y, z * z));
    float mx = -2.f * x, my = -2.f * y, mz = -2.f * z;
    f0 = make_uint4(pk2(hi16(mx), hi16(my)),
                    pk2(hi16(mz), hi16(residual(mx))),
                    pk2(hi16(residual(my)), hi16(residual(mz))),
                    pk2(hi16(p2), hi16(residual(p2))));
    f1 = make_uint4(f0.x, f0.y, f0.z, f1w);
}

// ---------------------------------------------------------------------------
// Prep: blocks 0..3 bucket-sort cloud b into 64 x-slabs (slab-major order,
// payload = orig index); blocks 4..35 = pd+sp+tran partials to slp slots.
// Also zeroes *out (mega, next launch, atomicAdds into it).
__global__ __launch_bounds__(256) void prep_kernel(const float* __restrict__ src,
                                                   const float* __restrict__ dp_all,
                                                   const float* __restrict__ drp,
                                                   const float* __restrict__ pw,
                                                   const float* __restrict__ rm,
                                                   float4* __restrict__ sorted,
                                                   int* __restrict__ slab_start,
                                                   float* __restrict__ slp,
                                                   float* __restrict__ out) {
    if (blockIdx.x < 4) {
        const int b = blockIdx.x;
        if (b == 0 && threadIdx.x == 0) *out = 0.f;
        __shared__ int hist[64], base_[65], cnt[64];
        const float* sb = src + (size_t)b * N_ * 3;
        if (threadIdx.x < 64) { hist[threadIdx.x] = 0; cnt[threadIdx.x] = 0; }
        __syncthreads();
        for (int i = threadIdx.x; i < N_; i += 256) {
            float x = sb[3 * i];
            int s = min(max((int)((x + 1.f) * 32.f), 0), 63);
            atomicAdd(&hist[s], 1);
        }
        __syncthreads();
        if (threadIdx.x == 0) {
            int run = 0;
            for (int s = 0; s < 64; ++s) { base_[s] = run; run += hist[s]; }
            base_[64] = N_;
        }
        __syncthreads();
        for (int i = threadIdx.x; i < N_; i += 256) {
            float x = sb[3 * i], y = sb[3 * i + 1], z = sb[3 * i + 2];
            int s = min(max((int)((x + 1.f) * 32.f), 0), 63);
            int pos = base_[s] + atomicAdd(&cnt[s], 1);
            sorted[(size_t)b * N_ + pos] = make_float4(x, y, z, __int_as_float(i));
        }
        if (threadIdx.x < 65) slab_start[b * 65 + threadIdx.x] = base_[threadIdx.x];
    } else {  // ---- pd + sp + tran
        __shared__ float red[4];
        const int PD_N = T_ * B_ * N_ * 3;
        const int SP_N = T_ * B_ * N_;
        const int stride = SL_BLOCKS * 256;
        const int gid = (blockIdx.x - 4) * 256 + threadIdx.x;
        float apd = 0.f;
        for (int i = gid; i < PD_N; i += stride) {
            float d = drp[i] - dp_all[i];
            apd = fmaf(d, d, apd);
        }
        float asp = 0.f;
        for (int i = gid; i < SP_N; i += stride) asp += fabsf(pw[i]);
        float atr = 0.f;
        if (gid < T_ * B_ * 3) {
            int t = gid / (B_ * 3);
            int b = (gid / 3) % B_;
            int rr = gid % 3;
            float v = rm[t * B_ * 16 + b * 16 + rr * 4 + 3];
            atr = v * v;
        }
        float acc = apd * (1.0f / B_) + asp * (1.0f / (B_ * N_)) + atr * (1.0f / B_);
        float s = block_reduce<4>(acc, red);
        if (threadIdx.x == 0) slp[blockIdx.x - 4] = s;  // unique slot
    }
}

// ---------------------------------------------------------------------------
// Mega: KNN role works on the x-sorted cloud, scanning 256-candidate chunks
// outward from the query tile's chunk; stops a direction when the slab-edge
// x-gap^2 exceeds a conservative d8 bound (min over 16 partial lane-8ths per
// query >= true merged 8th, maxed over the tile's 16 queries; NaN until lists
// fill -> no premature pruning; worst case = full scan). Chamfer role = r11.
__global__ __launch_bounds__(256, 6) void mega_kernel(const float* __restrict__ src,
                                                      const float* __restrict__ dp_all,
                                                      const float* __restrict__ tp,
                                                      const float4* __restrict__ sorted,
                                                      const int* __restrict__ slab_start,
                                                      const float* __restrict__ slp,
                                                      float* __restrict__ out) {
    __shared__ uint4 smem4[1024];  // 16 KiB (chamfer uses all; KNN uses half + extras)
    const f32x4 zero4 = {0.f, 0.f, 0.f, 0.f};

    const int g = blockIdx.x / GRP_SZ;
    const int r = blockIdx.x % GRP_SZ;

    if (r < GRP_KNN) {  // ================= KNN + ARAP role (pruned scan)
        const int knn_id = g * GRP_KNN + r;   // 0..1023
        uint4* alds = smem4;                  // 512 uint4 = 8 KiB (16 tiles/chunk)
        int*   ext  = (int*)(smem4 + 512);    // extras region
        int*   sls  = ext;                    // [0..64]  slab starts
        int*   cslo = ext + 65;               // [65..81] slab of pos c*256
        int*   cshi = ext + 82;               // [82..97] slab of pos c*256+255
        unsigned* bnd = (unsigned*)(ext + 98);// [98..161]
        int*   qor  = ext + 162;              // [162..177] query orig idx

        const int b   = knn_id >> 8;
        const int qt0 = (knn_id & 255) * 16;  // sorted-order query base
        const float4* sbp = sorted + (size_t)b * N_;
        const float* sb = src + (size_t)b * N_ * 3;

        const int wid  = __builtin_amdgcn_readfirstlane(threadIdx.x >> 6);
        const int lane = threadIdx.x & 63;
        const int n    = lane & 15;
        const int quad = lane >> 4;
        const int rbase = quad * 4;

        if (threadIdx.x < 65) sls[threadIdx.x] = slab_start[b * 65 + threadIdx.x];
        __syncthreads();
        if (threadIdx.x < 17) {
            int p = threadIdx.x * 256, s = 0;
            while (s < 63 && sls[s + 1] <= p) s++;
            cslo[threadIdx.x] = s;
        } else if (threadIdx.x < 33) {
            int p = (threadIdx.x - 17) * 256 + 255, s = 0;
            while (s < 63 && sls[s + 1] <= p) s++;
            cshi[threadIdx.x - 17] = s;
        }

        float4 qv = sbp[qt0 + n];
        const float qx = qv.x, qy = qv.y, qz = qv.z;
        const float q2 = fmaf(qx, qx, fmaf(qy, qy, qz * qz));
        float txmin = qx, txmax = qx;
        #pragma unroll
        for (int mk = 1; mk <= 8; mk <<= 1) {
            txmin = fminf(txmin, __shfl_xor(txmin, mk));
            txmax = fmaxf(txmax, __shfl_xor(txmax, mk));
        }

        bf16x8 bfrag = (bf16x8)(short)0;
        {
            short hx = hi16(qx), hy = hi16(qy), hz = hi16(qz);
            short lx = hi16(residual(qx)), ly = hi16(residual(qy)), lz = hi16(residual(qz));
            if (quad == 0) bfrag = (bf16x8){hx, hy, hz, hx, hy, hz, BF16_ONE, BF16_ONE};
            else if (quad == 1) bfrag = (bf16x8){lx, ly, lz, lx, ly, lz,
                                                 hi16(q2), hi16(residual(q2))};
        }

        unsigned a[K_];
        #pragma unroll
        for (int p = 0; p < K_; ++p) a[p] = 0xFFFFFFFFu;

        int cur = qt0 >> 8;                 // start: chunk containing the queries
        int cl = cur - 1, cr = cur + 1;
        bool dl = (cl < 0), dr = (cr >= NCHUNK);
        __syncthreads();  // cslo/cshi visible; alds free

        for (;;) {
            // ---- stage chunk `cur` (1 candidate/thread, coalesced float4)
            {
                float4 cd4 = sbp[cur * 256 + threadIdx.x];
                uint4 f0, f1;
                conv_frag(cd4.x, cd4.y, cd4.z, pk2(BF16_ONE, BF16_ONE), f0, f1);
                int tile = threadIdx.x >> 4, m = threadIdx.x & 15;
                alds[tile * 32 + m] = f0;  alds[tile * 32 + 16 + m] = f1;
            }
            __syncthreads();
            // ---- compute: this wave's 4 tiles, 2 batches of 2
            #pragma unroll
            for (int bt = 0; bt < 2; ++bt) {
                unsigned s8[8];
                #pragma unroll
                for (int h = 0; h < 2; ++h) {
                    const int tile = wid * 4 + bt * 2 + h;
                    const int tbg  = cur * 256 + tile * 16;  // sorted position base
                    bf16x8 af = (bf16x8)(short)0;
                    if (quad < 2) {
                        union { uint4 u; bf16x8 v; } cv;
                        cv.u = alds[tile * 32 + quad * 16 + n];
                        af = cv.v;
                    }
                    f32x4 d = __builtin_amdgcn_mfma_f32_16x16x32_bf16(af, bfrag, zero4, 0, 0, 0);
                    #pragma unroll
                    for (int rr = 0; rr < 4; ++rr)
                        s8[h * 4 + rr] = (__float_as_uint(d[rr]) & 0xFFFFF000u)
                                         | (unsigned)(tbg | (rbase + rr));
                    if (tbg == qt0) {  // self tile: exclude by sorted position
                        #pragma unroll
                        for (int rr = 0; rr < 4; ++rr)
                            if (rbase + rr == n) s8[h * 4 + rr] = 0xFFFFFFFFu;
                    }
                }
                sort8(s8);
                merge_top8(a, s8);
            }
            // ---- d8 bound: per-query min of partial lane-8ths, max over tile
            unsigned k8 = a[7];
            k8 = min(k8, (unsigned)__shfl_xor((int)k8, 16));
            k8 = min(k8, (unsigned)__shfl_xor((int)k8, 32));
            if (lane < 16) bnd[wid * 16 + lane] = k8;
            __syncthreads();  // bnd visible; alds consumed
            unsigned cm = min(min(bnd[n], bnd[16 + n]), min(bnd[32 + n], bnd[48 + n]));
            #pragma unroll
            for (int mk = 1; mk <= 8; mk <<= 1)
                cm = max(cm, (unsigned)__shfl_xor((int)cm, mk));
            float d8f = __uint_as_float(cm & 0xFFFFF000u) * 1.0005f + 1e-6f;  // NaN early

            float ledge = 0.f, redge = 0.f;
            if (!dr) ledge = -1.f + (float)cslo[cr] * 0.03125f;
            if (!dl) redge = -1.f + (float)(cshi[cl] + 1) * 0.03125f;
            if (!dr) { float dx = ledge - txmax; if (dx > 0.f && dx * dx > d8f) dr = true; }
            if (!dl) { float dx = txmin - redge; if (dx > 0.f && dx * dx > d8f) dl = true; }
            if (dl && dr) break;
            float er = dr ? 3e38f : fmaxf(ledge - txmax, 0.f);
            float el = dl ? 3e38f : fmaxf(txmin - redge, 0.f);
            if (!dr && (dl || er <= el)) { cur = cr; cr++; if (cr >= NCHUNK) dr = true; }
            else                          { cur = cl; cl--; if (cl < 0)      dl = true; }
            // loop top restages alds (free since bnd barrier)
        }

        // ---- fold row-quads, cross-wave merge, map to orig indices
        #pragma unroll
        for (int mk = 16; mk <= 32; mk <<= 1) {
            unsigned t[8];
            #pragma unroll
            for (int e = 0; e < K_; ++e) t[e] = __shfl_xor(a[e], mk, 64);
            merge_top8(a, t);
        }
        __syncthreads();
        unsigned* sm = (unsigned*)smem4;           // <576 ints, inside alds
        unsigned* nidx = (unsigned*)smem4 + 1024;  // 128 ints, inside alds
        if (lane < 16) {
            #pragma unroll
            for (int e = 0; e < K_; ++e) sm[(wid * 16 + n) * 9 + e] = a[e];
        }
        __syncthreads();
        if (threadIdx.x < 16) {
            const int q = threadIdx.x;
            unsigned md[K_];
            #pragma unroll
            for (int e = 0; e < K_; ++e) md[e] = sm[q * 9 + e];
            #pragma unroll
            for (int wv = 1; wv < 4; ++wv) {
                unsigned t[8];
                #pragma unroll
                for (int e = 0; e < K_; ++e) t[e] = sm[(wv * 16 + q) * 9 + e];
                merge_top8(md, t);
            }
            #pragma unroll
            for (int e = 0; e < K_; ++e)  // sorted pos -> orig index
                nidx[q * 8 + e] = (unsigned)__float_as_int(sbp[md[e] & 0xFFFu].w);
            qor[q] = __float_as_int(sbp[qt0 + q].w);
        }
        __syncthreads();

        // ---- fused ARAP (orig-index gathers)
        float acc = 0.f;
        if (threadIdx.x < 16 * K_) {
            const int q  = threadIdx.x >> 3;
            const int qi = qor[q];
            const int j  = (int)nidx[threadIdx.x];
            float sx = sb[3 * qi], sy = sb[3 * qi + 1], sz = sb[3 * qi + 2];
            float ex = sb[3 * j] - sx, ey = sb[3 * j + 1] - sy, ez = sb[3 * j + 2] - sz;
            float sd = sqrtf(fmaf(ex, ex, fmaf(ey, ey, ez * ez)) + 1e-5f);
            #pragma unroll
            for (int t = 0; t < T_; ++t) {
                const float* dpb = dp_all + ((size_t)(t * B_ + b)) * N_ * 3;
                float dx = dpb[3 * j] - dpb[3 * qi];
                float dy = dpb[3 * j + 1] - dpb[3 * qi + 1];
                float dz = dpb[3 * j + 2] - dpb[3 * qi + 2];
                float dd = sqrtf(fmaf(dx, dx, fmaf(dy, dy, dz * dz)) + 1e-5f);
                float df = dd - sd;
                acc = fmaf(df, df, acc);
            }
        }
        __syncthreads();
        float s = block_reduce<4>(acc, (float*)smem4);
        if (threadIdx.x == 0) atomicAdd(out, s * (1.0f / B_));

    } else {  // ================= chamfer role (r11 verbatim)
        const int cb = g * GRP_CH + (r - GRP_KNN);  // 0..383
        uint4* alds = smem4;
        const int tbd  = cb >> 4;
        const int slab = cb & 15;
        const int dir = tbd & 1;
        const int tb  = tbd >> 1;
        const int b = tb % B_, t = tb / B_;

        const float* dpb = dp_all + ((size_t)(t * B_ + b)) * N_ * 3;
        const float* tpb = tp + (size_t)b * N_ * 3;
        const float* cbase = dir ? dpb : tpb;
        const float* qbase = dir ? tpb : dpb;

        const int lane = threadIdx.x & 63;
        const int wave = threadIdx.x >> 6;
        const int quad = lane >> 4;
        const int n    = lane & 15;

        bf16x8 bfrag[4];
        float  q2r[4];
        #pragma unroll
        for (int s = 0; s < 4; ++s) {
            int qid = slab * 256 + wave * 64 + s * 16 + n;
            float x = qbase[3 * qid], y = qbase[3 * qid + 1], z = qbase[3 * qid + 2];
            q2r[s] = fmaf(x, x, fmaf(y, y, z * z));
            short hx = hi16(x), hy = hi16(y), hz = hi16(z);
            short lx = hi16(residual(x)), ly = hi16(residual(y)), lz = hi16(residual(z));
            if (quad == 0)
                bfrag[s] = (bf16x8){hx, hy, hz, hx, hy, hz, BF16_ONE, BF16_ONE};
            else if (quad == 1)
                bfrag[s] = (bf16x8){lx, ly, lz, lx, ly, lz, 0, 0};
            else
                bfrag[s] = (bf16x8)(short)0;
        }

        float run[4] = {3.4e38f, 3.4e38f, 3.4e38f, 3.4e38f};

        for (int w = 0; w < 8; ++w) {
            __syncthreads();
            #pragma unroll
            for (int rr = 0; rr < 2; ++rr) {
                int jloc = rr * 256 + threadIdx.x;
                int jg = w * 512 + jloc;
                uint4 f0, f1;
                conv_frag(cbase[3 * jg], cbase[3 * jg + 1], cbase[3 * jg + 2],
                          pk2(BF16_ONE, BF16_ONE), f0, f1);
                int tile = jloc >> 4, m = jloc & 15;
                alds[tile * 32 + m]      = f0;
                alds[tile * 32 + 16 + m] = f1;
            }
            __syncthreads();

            #pragma unroll 4
            for (int tile = 0; tile < 32; ++tile) {
                bf16x8 af = (bf16x8)(short)0;
                if (quad < 2) {
                    union { uint4 u; bf16x8 v; } cv;
                    cv.u = alds[tile * 32 + quad * 16 + n];
                    af = cv.v;
                }
                #pragma unroll
                for (int s = 0; s < 4; ++s) {
                    f32x4 d = __builtin_amdgcn_mfma_f32_16x16x32_bf16(af, bfrag[s], zero4, 0, 0, 0);
                    float r3 = fminf(fminf(d[0], d[1]), d[2]);
                    run[s] = fminf(fminf(run[s], r3), d[3]);
                }
            }
        }

        float vsum = 0.f;
        #pragma unroll
        for (int s = 0; s < 4; ++s) {
            float rr = run[s];
            rr = fminf(rr, __shfl_xor(rr, 32));
            rr = fminf(rr, __shfl_xor(rr, 16));
            if (lane < 16) vsum += rr + q2r[s];
        }
        __syncthreads();
        float ssum = block_reduce<4>(vsum, (float*)smem4);
        if (threadIdx.x == 0) {
            float add = ssum * (0.5f / B_);
            if (blockIdx.x == GROUPS * GRP_SZ - 1)  // fold prep's SL partials
                for (int i = 0; i < SL_BLOCKS; ++i) add += slp[i];
            atomicAdd(out, add);
        }
    }
}

// ---------------------------------------------------------------------------
extern "C" void kernel_launch(void* const* d_in, const int* in_sizes, int n_in,
                              void* d_out, int out_size, void* d_ws, size_t ws_size,
                              hipStream_t stream) {
    const float* pw  = (const float*)d_in[1];
    const float* drp = (const float*)d_in[2];
    const float* dp  = (const float*)d_in[3];
    const float* rm  = (const float*)d_in[4];
    const float* sp  = (const float*)d_in[5];
    const float* tp  = (const float*)d_in[6];
    float* out = (float*)d_out;

    float4* sorted     = (float4*)d_ws;                          // 256 KiB
    int*    slab_start = (int*)((char*)d_ws + 256 * 1024);       // 4*65 ints
    float*  slp        = (float*)((char*)d_ws + 258 * 1024);     // 32 floats

    prep_kernel<<<4 + SL_BLOCKS, 256, 0, stream>>>(sp, dp, drp, pw, rm,
                                                   sorted, slab_start, slp, out);
    mega_kernel<<<GROUPS * GRP_SZ, 256, 0, stream>>>(sp, dp, tp, sorted,
                                                     slab_start, slp, out);
}